// Round 11
// baseline (3665.139 us; speedup 1.0000x reference)
//
#include <hip/hip_runtime.h>
#include <hip/hip_bf16.h>
#include <stdint.h>

// ---------------------------------------------------------------------------
// NaiveLSTM: B=64, T=1024, I=512, H=512
//   phase 0: convert x->bf16; transpose W,U; init hist (slot0 = h0 = 0,
//            slots 1..1024 = bf16-NaN sentinel)
//   phase 1: xW = x @ W  (bf16 MFMA GEMM, global_load_lds staging)
//   phase 2: sequential LSTM. 128 blocks x 256 thr = 4 groups x 32 blocks;
//            block owns 16 h-cols, wave owns 4 cols x 4 gates = ONE 16-row
//            A-tile -> uf = 64 VGPR (fits ~120 live total, below RA's spill
//            point — the R8/R10 U-refeed (128KB/blk/step via L2/scratch) was
//            the dominant per-step cost). Lane's D-frag = all 4 gates of ONE
//            cell -> elementwise/c-state lane-local; publish via shfl-pack.
//            One lgkm-only barrier/step; xW(t+1) issued post-poll-detect.
// ---------------------------------------------------------------------------

typedef __attribute__((ext_vector_type(8))) short bf16x8;
typedef __attribute__((ext_vector_type(4))) float f32x4;

constexpr int T_STEPS = 1024;
constexpr int HS = 512;
constexpr int NGROUP = 4;                       // batch groups, 16 rows each
constexpr unsigned SENT = 0x7FC07FC0u;          // bf16 NaN pair; h finite always
constexpr int HIST_SLOT_U32 = 16 * 512 / 2;     // 4096 u32 = 16KB per step/group

__device__ __forceinline__ unsigned short f2bf(float f) {
  unsigned u = __float_as_uint(f);
  u += 0x7fffu + ((u >> 16) & 1u);              // RNE
  return (unsigned short)(u >> 16);
}
__device__ __forceinline__ float bf2f(unsigned short u) {
  return __uint_as_float((unsigned)u << 16);
}

__device__ __forceinline__ float fast_sig(float x) {
  return __builtin_amdgcn_rcpf(1.f + __expf(-x));
}
__device__ __forceinline__ float fast_tanh(float x) {
  return 2.f * __builtin_amdgcn_rcpf(1.f + __expf(-2.f * x)) - 1.f;
}

// ----- system-scope (LLC, cross-XCD safe) ops — proven rounds 1-10 -----
__device__ __forceinline__ void stg_u32_llc(void* p, unsigned v) {
  asm volatile("global_store_dword %0, %1, off sc0 sc1" :: "v"(p), "v"(v) : "memory");
}
__device__ __forceinline__ void ldg_64B_llc(const void* p, uint4& a, uint4& b, uint4& c, uint4& d) {
  const char* q = (const char*)p;
  asm volatile(
      "global_load_dwordx4 %0, %4, off sc0 sc1\n\t"
      "global_load_dwordx4 %1, %5, off sc0 sc1\n\t"
      "global_load_dwordx4 %2, %6, off sc0 sc1\n\t"
      "global_load_dwordx4 %3, %7, off sc0 sc1\n\t"
      "s_waitcnt vmcnt(0)"
      : "=&v"(a), "=&v"(b), "=&v"(c), "=&v"(d)
      : "v"(q), "v"(q + 16), "v"(q + 32), "v"(q + 48)
      : "memory");
}

// raw barrier: drain LDS ops only (NOT vmem) then s_barrier
__device__ __forceinline__ void bar_lds() {
  asm volatile("s_waitcnt lgkmcnt(0)" ::: "memory");
  __builtin_amdgcn_s_barrier();
}

// ---------------------------------------------------------------------------
__global__ __launch_bounds__(256) void conv_f32_to_bf16(const float* __restrict__ in,
                                                        uint4* __restrict__ out, int n16) {
  int i = blockIdx.x * 256 + threadIdx.x;
  const int stride = gridDim.x * 256;
  for (; i < n16; i += stride) {
    float4 a = ((const float4*)in)[2 * i];
    float4 b = ((const float4*)in)[2 * i + 1];
    uint4 o;
    o.x = (unsigned)f2bf(a.x) | ((unsigned)f2bf(a.y) << 16);
    o.y = (unsigned)f2bf(a.z) | ((unsigned)f2bf(a.w) << 16);
    o.z = (unsigned)f2bf(b.x) | ((unsigned)f2bf(b.y) << 16);
    o.w = (unsigned)f2bf(b.z) | ((unsigned)f2bf(b.w) << 16);
    out[i] = o;
  }
}

// ---------------------------------------------------------------------------
__global__ __launch_bounds__(256) void transpose_to_bf16(const float* __restrict__ in,
                                                         unsigned short* __restrict__ out,
                                                         int R, int C) {
  __shared__ unsigned short tile[64][72];
  const int tx = threadIdx.x & 63, ty = threadIdx.x >> 6;
  const int c0 = blockIdx.x * 64, r0 = blockIdx.y * 64;
#pragma unroll
  for (int rr = ty; rr < 64; rr += 4)
    tile[rr][tx] = f2bf(in[(size_t)(r0 + rr) * C + c0 + tx]);
  __syncthreads();
#pragma unroll
  for (int cc = ty; cc < 64; cc += 4)
    out[(size_t)(c0 + cc) * R + r0 + tx] = tile[tx][cc];
}

// ---------------------------------------------------------------------------
// hist init: per group, slot 0 (h0) = 0.0, slots 1..1024 = sentinel.
// Runs EVERY launch (graph replays reuse the buffer).
// ---------------------------------------------------------------------------
__global__ __launch_bounds__(256) void init_hist(uint4* __restrict__ hist4) {
  const unsigned per_g = 1025u * 1024u;          // uint4 per 16KB-slot group region
  const unsigned total = NGROUP * per_g;
  unsigned i = blockIdx.x * 256 + threadIdx.x;
  const unsigned stride = gridDim.x * 256;
  for (; i < total; i += stride) {
    const unsigned w = i % per_g;
    const unsigned v = (w < 1024u) ? 0u : SENT;  // slot 0 = 1024 uint4
    hist4[i] = make_uint4(v, v, v, v);
  }
}

// ---------------------------------------------------------------------------
// Phase 1 GEMM (unchanged, proven): 128x128 tile, BK=64, global_load_lds.
// ---------------------------------------------------------------------------
__global__ __launch_bounds__(256, 1) void gemm_xw(const unsigned short* __restrict__ A,
                                                  const unsigned short* __restrict__ Bt,
                                                  unsigned short* __restrict__ C) {
  __shared__ __align__(16) char Al[128 * 128];
  __shared__ __align__(16) char Bl[128 * 128];
  const int tid = threadIdx.x, lane = tid & 63, wave = tid >> 6;
  const int n0 = blockIdx.x * 128;
  const size_t m0 = (size_t)blockIdx.y * 128;
  const int wm = wave >> 1, wn = wave & 1;
  f32x4 acc[4][4] = {};

  for (int ks = 0; ks < 8; ++ks) {
    const int k0 = ks * 64;
    if (ks) __syncthreads();
#pragma unroll
    for (int p = 0; p < 4; ++p) {
      const int off = p * 4096 + wave * 1024 + lane * 16;
      const int row = off >> 7, kb = off & 127;
      const unsigned short* ga = A + (m0 + row) * 512 + k0 + (kb >> 1);
      const unsigned short* gb = Bt + (size_t)(n0 + row) * 512 + k0 + (kb >> 1);
      __builtin_amdgcn_global_load_lds(
          (const __attribute__((address_space(1))) void*)ga,
          (__attribute__((address_space(3))) void*)(Al + p * 4096 + wave * 1024), 16, 0, 0);
      __builtin_amdgcn_global_load_lds(
          (const __attribute__((address_space(1))) void*)gb,
          (__attribute__((address_space(3))) void*)(Bl + p * 4096 + wave * 1024), 16, 0, 0);
    }
    __syncthreads();
#pragma unroll
    for (int kk = 0; kk < 2; ++kk) {
      const int kb = (kk * 32 + (lane >> 4) * 8) * 2;
      bf16x8 av[4], bv[4];
#pragma unroll
      for (int i = 0; i < 4; ++i)
        av[i] = *(const bf16x8*)(Al + (wm * 64 + i * 16 + (lane & 15)) * 128 + kb);
#pragma unroll
      for (int j = 0; j < 4; ++j)
        bv[j] = *(const bf16x8*)(Bl + (wn * 64 + j * 16 + (lane & 15)) * 128 + kb);
#pragma unroll
      for (int i = 0; i < 4; ++i)
#pragma unroll
        for (int j = 0; j < 4; ++j)
          acc[i][j] = __builtin_amdgcn_mfma_f32_16x16x32_bf16(av[i], bv[j], acc[i][j], 0, 0, 0);
    }
  }
#pragma unroll
  for (int i = 0; i < 4; ++i)
#pragma unroll
    for (int j = 0; j < 4; ++j) {
      const int col = n0 + wn * 64 + j * 16 + (lane & 15);
#pragma unroll
      for (int r = 0; r < 4; ++r) {
        const int row = wm * 64 + i * 16 + (lane >> 4) * 4 + r;
        C[(m0 + row) * (size_t)2048 + col] = f2bf(acc[i][j][r]);
      }
    }
}

// ---------------------------------------------------------------------------
// Phase 2: sequential LSTM. 128 blocks x 256 threads (4 waves).
// group g = bid&3 (rows g*16..+16), bg = bid>>2 in [0,32) owns h-cols
// [bg*16, bg*16+16). Wave w owns cols c0+4w..+4 x all 4 gates = one 16-row
// A-tile; uf[16] = 64 VGPR, total live ~120 -> RA keeps U resident.
// D-frag: lane (b=lane&15, q=lane>>4) holds gates r=0..3 of cell
// (b, c0+4w+q) -> fully lane-local elementwise, c-state in 1 register.
// Per step: poll (only poll loads pending) -> issue xW(t+1) -> stage ->
// lgkm-barrier -> 2 MFMA chains of 8 -> elementwise (1 cell) -> shfl-pack
// publish u32 (sc1) -> scalar f32 out (lazy).
// ---------------------------------------------------------------------------
__global__ __launch_bounds__(256, 1) void lstm_seq(const unsigned short* __restrict__ xW, // bf16 [65536][2048]
                                                   const unsigned short* __restrict__ Ut, // bf16 [2048][512]
                                                   const float* __restrict__ bias,        // [2048]
                                                   float* __restrict__ out,
                                                   unsigned* __restrict__ hist) {
  __shared__ __align__(16) unsigned short hl[2][16 * 512];  // dbuf, 32KB

  const int tid = threadIdx.x, lane = tid & 63, wave = tid >> 6;
  const int g = blockIdx.x & 3;
  const int bg = blockIdx.x >> 2;
  const int c0 = bg * 16;
  const int bm0 = g * 16;

  // A-side (U-frag) roles: tile row n = lane&15 -> (colpair = n>>2, gate = n&3)
  const int r16 = lane & 15;
  const int gate_a = r16 & 3;
  const int cp_a = r16 >> 2;
  const int kq = lane >> 4;             // k-chunk id (8 elems within ks-slice)
  // D-side (output) roles: lane = (b, q); n = q*4+r -> gate r, col c0+4w+q
  const int b = lane & 15;
  const int q = lane >> 4;
  const int col = c0 + wave * 4 + q;    // this lane's single output col
  const int bglob = bm0 + b;

  // ---- one-time: U A-tile fragments, 16 ks x 4 VGPR = 64 VGPR (resident) ----
  bf16x8 uf[16];
  {
    const unsigned short* ua =
        Ut + (size_t)(gate_a * 512 + c0 + wave * 4 + cp_a) * 512 + kq * 8;
#pragma unroll
    for (int ks = 0; ks < 16; ++ks) uf[ks] = *(const bf16x8*)(ua + ks * 32);
  }

  float bias_r[4];
#pragma unroll
  for (int r = 0; r < 4; ++r) bias_r[r] = bias[r * 512 + col];
  float c_state = 0.f;

  // h B-frag read (from hl, swizzled): row = lane&15, k-chunk kq
  const int am = lane & 15;
  const int asw = (am & 7) << 4;
  const int kgb = kq * 16;
  // stage roles (thread tid stages 64B of row tid>>4)
  const int rowb = (tid >> 4) * 1024;
  const int colb = (tid & 15) * 64;
  const int sw = ((tid >> 4) & 7) << 4;

  // prologue: xW(0) — 4 scalar bf16 loads (gate-strided)
  const unsigned short* xwrow = xW + (size_t)bglob * T_STEPS * 2048;
  unsigned short xwv[4], xwn[4];
#pragma unroll
  for (int r = 0; r < 4; ++r) xwv[r] = xwrow[r * 512 + col];

  __syncthreads();

  for (int t = 0; t < T_STEPS; ++t) {
    // ---- poll h_t data (sentinel; only poll loads pending -> pure LLC RT) ----
    uint4 pa, pb, pc, pd;
    {
      const char* hb = (const char*)hist + (size_t)(g * 1025 + t) * 16384 + tid * 64;
      for (;;) {
        ldg_64B_llc(hb, pa, pb, pc, pd);
        const bool bad = (pa.x == SENT) | (pa.y == SENT) | (pa.z == SENT) | (pa.w == SENT) |
                         (pb.x == SENT) | (pb.y == SENT) | (pb.z == SENT) | (pb.w == SENT) |
                         (pc.x == SENT) | (pc.y == SENT) | (pc.z == SENT) | (pc.w == SENT) |
                         (pd.x == SENT) | (pd.y == SENT) | (pd.z == SENT) | (pd.w == SENT);
        if (!bad) break;
      }
    }
    // ---- issue xW(t+1) now: retires under MFMA + next poll, never at barrier ----
    {
      const int tn = (t + 1 < T_STEPS) ? t + 1 : t;
      const unsigned short* bn = xwrow + (size_t)tn * 2048;
#pragma unroll
      for (int r = 0; r < 4; ++r) xwn[r] = bn[r * 512 + col];
    }
    // ---- stage h_t to LDS (swizzled), double-buffered ----
    {
      char* dst = (char*)hl[t & 1];
      *(uint4*)(dst + ((rowb + colb) ^ sw)) = pa;
      *(uint4*)(dst + ((rowb + colb + 16) ^ sw)) = pb;
      *(uint4*)(dst + ((rowb + colb + 32) ^ sw)) = pc;
      *(uint4*)(dst + ((rowb + colb + 48) ^ sw)) = pd;
    }
    bar_lds();  // lgkmcnt(0) + s_barrier — vmem stays in flight

    // ---- acc = bias + xW(t) + h@U : 2 independent MFMA chains of 8 ----
    f32x4 a1, b1 = {0.f, 0.f, 0.f, 0.f};
#pragma unroll
    for (int r = 0; r < 4; ++r) a1[r] = bias_r[r] + bf2f(xwv[r]);
    const char* hbase = (const char*)hl[t & 1];
#pragma unroll
    for (int ks = 0; ks < 16; ks += 2) {
      const bf16x8 h0 = *(const bf16x8*)(hbase + ((am * 1024 + ks * 64 + kgb) ^ asw));
      const bf16x8 h1 = *(const bf16x8*)(hbase + ((am * 1024 + (ks + 1) * 64 + kgb) ^ asw));
      a1 = __builtin_amdgcn_mfma_f32_16x16x32_bf16(uf[ks], h0, a1, 0, 0, 0);
      b1 = __builtin_amdgcn_mfma_f32_16x16x32_bf16(uf[ks + 1], h1, b1, 0, 0, 0);
    }
    const f32x4 acc = a1 + b1;

    // ---- lane-local elementwise: exactly ONE cell (bglob, col) ----
    const float it = fast_sig(acc[0]);
    const float ft = fast_sig(acc[1]);
    const float gt = fast_tanh(acc[2]);
    const float ot = fast_sig(acc[3]);
    c_state = ft * c_state + it * gt;
    const float hv = ot * fast_tanh(c_state);

    // ---- publish h_{t+1}: pack col pair across lane^16, half-lanes store ----
    {
      const unsigned own = (unsigned)f2bf(hv);
      const unsigned part = (unsigned)__shfl_xor((int)own, 16);
      if (!(q & 1)) {
        const unsigned hp = own | (part << 16);
        stg_u32_llc(hist + (size_t)(g * 1025 + t + 1) * HIST_SLOT_U32 + b * 256 + (col >> 1), hp);
      }
    }
    // ---- fp32 hidden_seq (retires lazily) ----
    out[((size_t)bglob * T_STEPS + t) * HS + col] = hv;
    if (t == T_STEPS - 1) {
      const size_t hs_total = (size_t)64 * T_STEPS * HS;
      out[hs_total + (size_t)bglob * HS + col] = hv;
      out[hs_total + 64 * HS + (size_t)bglob * HS + col] = c_state;
    }
#pragma unroll
    for (int r = 0; r < 4; ++r) xwv[r] = xwn[r];
    // single barrier per step is sufficient: stage(t+2) into hl[t&1] can only
    // happen after poll(t+2) -> publishes(t+1) -> each wave passed bar(t+1)
    // -> every wave's mfma(t) reads of hl[t&1] are complete.
  }
}

// ---------------------------------------------------------------------------
extern "C" void kernel_launch(void* const* d_in, const int* in_sizes, int n_in,
                              void* d_out, int out_size, void* d_ws, size_t ws_size,
                              hipStream_t stream) {
  const float* x = (const float*)d_in[0];
  const float* W = (const float*)d_in[1];
  const float* U = (const float*)d_in[2];
  const float* bias = (const float*)d_in[3];
  float* out = (float*)d_out;
  char* ws = (char*)d_ws;

  size_t off = 0;
  unsigned short* x_bf = (unsigned short*)(ws + off); off += (size_t)65536 * 512 * 2;        // 64MB
  unsigned short* Wt = (unsigned short*)(ws + off);   off += (size_t)2048 * 512 * 2;         // 2MB
  unsigned short* Ut = (unsigned short*)(ws + off);   off += (size_t)2048 * 512 * 2;         // 2MB
  unsigned* hist = (unsigned*)(ws + off);             off += (size_t)NGROUP * 1025 * 16384;  // 67MB
  unsigned short* xWb = (unsigned short*)(ws + off);  off += (size_t)65536 * 2048 * 2;       // 256MB
  if (ws_size < off) return;

  conv_f32_to_bf16<<<4096, 256, 0, stream>>>(x, (uint4*)x_bf, 33554432 / 8);
  transpose_to_bf16<<<dim3(32, 8), 256, 0, stream>>>(W, Wt, 512, 2048);
  transpose_to_bf16<<<dim3(32, 8), 256, 0, stream>>>(U, Ut, 512, 2048);
  init_hist<<<2048, 256, 0, stream>>>((uint4*)hist);
  gemm_xw<<<dim3(16, 512), 256, 0, stream>>>(x_bf, Wt, xWb);
  lstm_seq<<<128, 256, 0, stream>>>(xWb, Ut, bias, out, hist);
}

// Round 12
// 2210.536 us; speedup vs baseline: 1.6580x; 1.6580x over previous
//
#include <hip/hip_runtime.h>
#include <hip/hip_bf16.h>
#include <stdint.h>

// ---------------------------------------------------------------------------
// NaiveLSTM: B=64, T=1024, I=512, H=512
//   phase 0: convert x->bf16; transpose W,U; init hist (slot0 = h0 = 0,
//            slots 1..1024 = bf16-NaN sentinel)
//   phase 1: xW = x @ W  (bf16 MFMA GEMM, global_load_lds staging)
//   phase 2: sequential LSTM — EXACT round-2 structure (proven 2546us:
//            64 blocks x 256 thr, 4 groups x 16 blocks, U-frag reload/step,
//            2-chain MFMA, gl gate-routing, 2 barriers) with ONE coupled
//            change: xW loads are one-step-ahead (issued post-poll-detect)
//            and both barriers are lgkmcnt-only (s_barrier without vmem
//            drain), so neither the poll's vmcnt(0) nor any barrier ever
//            waits on the ~900-cyc cold-HBM xW loads.
// ---------------------------------------------------------------------------

typedef __attribute__((ext_vector_type(8))) short bf16x8;
typedef __attribute__((ext_vector_type(4))) float f32x4;

constexpr int T_STEPS = 1024;
constexpr int HS = 512;
constexpr int G4 = 2048;
constexpr int NGROUP = 4;
constexpr unsigned SENT = 0x7FC07FC0u;          // bf16 NaN pair — h can never be NaN
constexpr int HIST_SLOT_U32 = 16 * 512 / 2;     // 4096 u32 = 16KB per step per group

__device__ __forceinline__ unsigned short f2bf(float f) {
  unsigned u = __float_as_uint(f);
  u += 0x7fffu + ((u >> 16) & 1u);              // RNE
  return (unsigned short)(u >> 16);
}
__device__ __forceinline__ float bf_lo(unsigned u) { return __uint_as_float(u << 16); }
__device__ __forceinline__ float bf_hi(unsigned u) { return __uint_as_float(u & 0xffff0000u); }

__device__ __forceinline__ float fast_sig(float x) {
  return __builtin_amdgcn_rcpf(1.f + __expf(-x));
}
__device__ __forceinline__ float fast_tanh(float x) {
  return 2.f * __builtin_amdgcn_rcpf(1.f + __expf(-2.f * x)) - 1.f;
}

// ----- LLC-coherent (cross-XCD safe) memory ops -----
__device__ __forceinline__ void stg_u32_llc(void* p, unsigned v) {
  asm volatile("global_store_dword %0, %1, off sc0 sc1" :: "v"(p), "v"(v) : "memory");
}
__device__ __forceinline__ void ldg_64B_llc(const void* p, uint4& a, uint4& b, uint4& c, uint4& d) {
  const char* q = (const char*)p;
  asm volatile(
      "global_load_dwordx4 %0, %4, off sc0 sc1\n\t"
      "global_load_dwordx4 %1, %5, off sc0 sc1\n\t"
      "global_load_dwordx4 %2, %6, off sc0 sc1\n\t"
      "global_load_dwordx4 %3, %7, off sc0 sc1\n\t"
      "s_waitcnt vmcnt(0)"
      : "=&v"(a), "=&v"(b), "=&v"(c), "=&v"(d)
      : "v"(q), "v"(q + 16), "v"(q + 32), "v"(q + 48)
      : "memory");
}
// raw barrier: drain LDS ops only (NOT vmem) then s_barrier
__device__ __forceinline__ void bar_lds() {
  asm volatile("s_waitcnt lgkmcnt(0)" ::: "memory");
  __builtin_amdgcn_s_barrier();
}

// ---------------------------------------------------------------------------
__global__ __launch_bounds__(256) void conv_f32_to_bf16(const float* __restrict__ in,
                                                        uint4* __restrict__ out, int n16) {
  int i = blockIdx.x * 256 + threadIdx.x;
  const int stride = gridDim.x * 256;
  for (; i < n16; i += stride) {
    float4 a = ((const float4*)in)[2 * i];
    float4 b = ((const float4*)in)[2 * i + 1];
    uint4 o;
    o.x = (unsigned)f2bf(a.x) | ((unsigned)f2bf(a.y) << 16);
    o.y = (unsigned)f2bf(a.z) | ((unsigned)f2bf(a.w) << 16);
    o.z = (unsigned)f2bf(b.x) | ((unsigned)f2bf(b.y) << 16);
    o.w = (unsigned)f2bf(b.z) | ((unsigned)f2bf(b.w) << 16);
    out[i] = o;
  }
}

// ---------------------------------------------------------------------------
__global__ __launch_bounds__(256) void transpose_to_bf16(const float* __restrict__ in,
                                                         unsigned short* __restrict__ out,
                                                         int R, int C) {
  __shared__ unsigned short tile[64][72];
  const int tx = threadIdx.x & 63, ty = threadIdx.x >> 6;
  const int c0 = blockIdx.x * 64, r0 = blockIdx.y * 64;
#pragma unroll
  for (int rr = ty; rr < 64; rr += 4)
    tile[rr][tx] = f2bf(in[(size_t)(r0 + rr) * C + c0 + tx]);
  __syncthreads();
#pragma unroll
  for (int cc = ty; cc < 64; cc += 4)
    out[(size_t)(c0 + cc) * R + r0 + tx] = tile[tx][cc];
}

// ---------------------------------------------------------------------------
// hist init: per group, slot 0 (h0) = 0.0, slots 1..1024 = sentinel.
// Must run EVERY launch (graph replays reuse the buffer).
// ---------------------------------------------------------------------------
__global__ __launch_bounds__(256) void init_hist(uint4* __restrict__ hist4) {
  const unsigned per_g = 1025u * 1024u;          // uint4 per group region
  const unsigned total = NGROUP * per_g;
  unsigned i = blockIdx.x * 256 + threadIdx.x;
  const unsigned stride = gridDim.x * 256;
  for (; i < total; i += stride) {
    const unsigned w = i % per_g;
    const unsigned v = (w < 1024u) ? 0u : SENT;  // slot 0 = 1024 uint4
    hist4[i] = make_uint4(v, v, v, v);
  }
}

// ---------------------------------------------------------------------------
// Phase 1 GEMM (unchanged, proven): 128x128 tile, BK=64, global_load_lds.
// ---------------------------------------------------------------------------
__global__ __launch_bounds__(256, 1) void gemm_xw(const unsigned short* __restrict__ A,
                                                  const unsigned short* __restrict__ Bt,
                                                  unsigned short* __restrict__ C) {
  __shared__ __align__(16) char Al[128 * 128];
  __shared__ __align__(16) char Bl[128 * 128];
  const int tid = threadIdx.x, lane = tid & 63, wave = tid >> 6;
  const int n0 = blockIdx.x * 128;
  const size_t m0 = (size_t)blockIdx.y * 128;
  const int wm = wave >> 1, wn = wave & 1;
  f32x4 acc[4][4] = {};

  for (int ks = 0; ks < 8; ++ks) {
    const int k0 = ks * 64;
    if (ks) __syncthreads();
#pragma unroll
    for (int p = 0; p < 4; ++p) {
      const int off = p * 4096 + wave * 1024 + lane * 16;
      const int row = off >> 7, kb = off & 127;
      const unsigned short* ga = A + (m0 + row) * 512 + k0 + (kb >> 1);
      const unsigned short* gb = Bt + (size_t)(n0 + row) * 512 + k0 + (kb >> 1);
      __builtin_amdgcn_global_load_lds(
          (const __attribute__((address_space(1))) void*)ga,
          (__attribute__((address_space(3))) void*)(Al + p * 4096 + wave * 1024), 16, 0, 0);
      __builtin_amdgcn_global_load_lds(
          (const __attribute__((address_space(1))) void*)gb,
          (__attribute__((address_space(3))) void*)(Bl + p * 4096 + wave * 1024), 16, 0, 0);
    }
    __syncthreads();
#pragma unroll
    for (int kk = 0; kk < 2; ++kk) {
      const int kb = (kk * 32 + (lane >> 4) * 8) * 2;
      bf16x8 av[4], bv[4];
#pragma unroll
      for (int i = 0; i < 4; ++i)
        av[i] = *(const bf16x8*)(Al + (wm * 64 + i * 16 + (lane & 15)) * 128 + kb);
#pragma unroll
      for (int j = 0; j < 4; ++j)
        bv[j] = *(const bf16x8*)(Bl + (wn * 64 + j * 16 + (lane & 15)) * 128 + kb);
#pragma unroll
      for (int i = 0; i < 4; ++i)
#pragma unroll
        for (int j = 0; j < 4; ++j)
          acc[i][j] = __builtin_amdgcn_mfma_f32_16x16x32_bf16(av[i], bv[j], acc[i][j], 0, 0, 0);
    }
  }
#pragma unroll
  for (int i = 0; i < 4; ++i)
#pragma unroll
    for (int j = 0; j < 4; ++j) {
      const int col = n0 + wn * 64 + j * 16 + (lane & 15);
#pragma unroll
      for (int r = 0; r < 4; ++r) {
        const int row = wm * 64 + i * 16 + (lane >> 4) * 4 + r;
        C[(m0 + row) * (size_t)2048 + col] = f2bf(acc[i][j][r]);
      }
    }
}

// ---------------------------------------------------------------------------
// Phase 2: sequential LSTM — R2 structure verbatim, with xW one-step-ahead
// and lgkm-only barriers. 64 blocks x 256 threads.
// group g = bid&3 (16 batch rows), bg = bid>>2 owns h-cols [bg*32, bg*32+32).
// U fragments in "registers" (compiler remats from L2 per step — proven OK).
// wave w computes gate w's 16x32 tile; gates routed via gl for elementwise.
// ---------------------------------------------------------------------------
__global__ __launch_bounds__(256, 1) void lstm_seq(const unsigned* __restrict__ xW,       // bf16 pairs [65536][1024]
                                                   const unsigned short* __restrict__ Ut, // bf16 [2048][512]
                                                   const float* __restrict__ bias,        // [2048]
                                                   float* __restrict__ out,
                                                   unsigned* __restrict__ hist) {
  __shared__ __align__(16) unsigned short hl[2][16 * 512];  // double-buffered, 32KB
  __shared__ float gl[4][16][32];                            // gate tiles, 8KB
  __shared__ float cl[16][32];                               // cell state, 2KB

  const int tid = threadIdx.x, lane = tid & 63, wave = tid >> 6;
  const int g = blockIdx.x & 3;
  const int bg = blockIdx.x >> 2;
  const int c0 = bg * 32;
  const int bm0 = g * 16;

  // ---- one-time: U^T fragments (wave = gate) ----
  bf16x8 uf[16][2];
#pragma unroll
  for (int ks = 0; ks < 16; ++ks)
#pragma unroll
    for (int j = 0; j < 2; ++j)
      uf[ks][j] = *(const bf16x8*)(Ut +
          (size_t)(wave * 512 + c0 + j * 16 + (lane & 15)) * 512 + ks * 32 + (lane >> 4) * 8);

  if (tid < 128) ((float4*)cl)[tid] = make_float4(0.f, 0.f, 0.f, 0.f);

  const int m = tid >> 4;          // batch row within group
  const int np = (tid & 15) * 2;   // col pair within block's 32 cols
  float bs[4][2];
#pragma unroll
  for (int gg = 0; gg < 4; ++gg) {
    bs[gg][0] = bias[gg * 512 + c0 + np];
    bs[gg][1] = bias[gg * 512 + c0 + np + 1];
  }

  const int am = lane & 15;
  const int asw = (am & 7) << 4;
  const int kgb = (lane >> 4) * 16;           // byte offset of lane's k-chunk
  const int rowb = (tid >> 4) * 1024;         // h-staging LDS offsets
  const int colb = (tid & 15) * 64;
  const int sw = ((tid >> 4) & 7) << 4;

  // prologue: xW(0)
  unsigned xwv[4];
  {
    const unsigned* base = xW + (size_t)(bm0 + m) * T_STEPS * (G4 / 2);
#pragma unroll
    for (int gg = 0; gg < 4; ++gg) xwv[gg] = base[(gg * 512 + c0 + np) >> 1];
  }

  __syncthreads();  // cl init visible

  for (int t = 0; t < T_STEPS; ++t) {
    // ---- poll h_t DATA (sentinel). Only poll loads + long-retired ops are
    //      outstanding -> vmcnt(0) here is a pure LLC round trip. ----
    uint4 a, b, c, d;
    {
      const char* hb = (const char*)hist + (size_t)(g * 1025 + t) * 16384 + tid * 64;
      for (;;) {
        ldg_64B_llc(hb, a, b, c, d);
        const bool bad = (a.x == SENT) | (a.y == SENT) | (a.z == SENT) | (a.w == SENT) |
                         (b.x == SENT) | (b.y == SENT) | (b.z == SENT) | (b.w == SENT) |
                         (c.x == SENT) | (c.y == SENT) | (c.z == SENT) | (c.w == SENT) |
                         (d.x == SENT) | (d.y == SENT) | (d.z == SENT) | (d.w == SENT);
        if (!bad) break;
      }
    }
    // ---- issue xW(t+1) NOW: retires under MFMA/elementwise/next-poll; the
    //      lgkm-only barriers below never drain it. ----
    unsigned xwn[4];
    {
      const int tn = (t + 1 < T_STEPS) ? t + 1 : t;
      const unsigned* basen = xW + ((size_t)(bm0 + m) * T_STEPS + tn) * (G4 / 2);
#pragma unroll
      for (int gg = 0; gg < 4; ++gg) xwn[gg] = basen[(gg * 512 + c0 + np) >> 1];
    }
    // ---- stage h_t to LDS (swizzled) ----
    {
      char* dst = (char*)hl[t & 1];
      *(uint4*)(dst + ((rowb + colb) ^ sw)) = a;
      *(uint4*)(dst + ((rowb + colb + 16) ^ sw)) = b;
      *(uint4*)(dst + ((rowb + colb + 32) ^ sw)) = c;
      *(uint4*)(dst + ((rowb + colb + 48) ^ sw)) = d;
    }
    bar_lds();  // sync A (lgkm only — vmem stays in flight)

    // ---- h_t @ U slice: wave = gate, two 16x16 n-tiles, K=512 ----
    f32x4 acc0 = {0.f, 0.f, 0.f, 0.f}, acc1 = {0.f, 0.f, 0.f, 0.f};
    const char* hbase = (const char*)hl[t & 1];
#pragma unroll
    for (int ks = 0; ks < 16; ++ks) {
      bf16x8 av = *(const bf16x8*)(hbase + ((am * 1024 + ks * 64 + kgb) ^ asw));
      acc0 = __builtin_amdgcn_mfma_f32_16x16x32_bf16(av, uf[ks][0], acc0, 0, 0, 0);
      acc1 = __builtin_amdgcn_mfma_f32_16x16x32_bf16(av, uf[ks][1], acc1, 0, 0, 0);
    }
    // route gate tiles through LDS
    {
      const int col = lane & 15, row4 = (lane >> 4) * 4;
#pragma unroll
      for (int r = 0; r < 4; ++r) {
        gl[wave][row4 + r][col] = acc0[r];
        gl[wave][row4 + r][col + 16] = acc1[r];
      }
    }
    bar_lds();  // sync B (lgkm only)

    // ---- elementwise LSTM cell for this thread's (m, np..np+1) ----
    {
      float h0, h1, cA, cB;
      {
        const int nc = np;
        const float xi = gl[0][m][nc] + bf_lo(xwv[0]) + bs[0][0];
        const float xf = gl[1][m][nc] + bf_lo(xwv[1]) + bs[1][0];
        const float xg = gl[2][m][nc] + bf_lo(xwv[2]) + bs[2][0];
        const float xo = gl[3][m][nc] + bf_lo(xwv[3]) + bs[3][0];
        const float it = fast_sig(xi), ft = fast_sig(xf);
        const float gt = fast_tanh(xg), ot = fast_sig(xo);
        cA = ft * cl[m][nc] + it * gt;
        h0 = ot * fast_tanh(cA);
        cl[m][nc] = cA;
      }
      {
        const int nc = np + 1;
        const float xi = gl[0][m][nc] + bf_hi(xwv[0]) + bs[0][1];
        const float xf = gl[1][m][nc] + bf_hi(xwv[1]) + bs[1][1];
        const float xg = gl[2][m][nc] + bf_hi(xwv[2]) + bs[2][1];
        const float xo = gl[3][m][nc] + bf_hi(xwv[3]) + bs[3][1];
        const float it = fast_sig(xi), ft = fast_sig(xf);
        const float gt = fast_tanh(xg), ot = fast_sig(xo);
        cB = ft * cl[m][nc] + it * gt;
        h1 = ot * fast_tanh(cB);
        cl[m][nc] = cB;
      }
      // publish h_{t+1} FIRST (inter-block critical path)
      const unsigned hp = (unsigned)f2bf(h0) | ((unsigned)f2bf(h1) << 16);
      stg_u32_llc(hist + (size_t)(g * 1025 + t + 1) * HIST_SLOT_U32 + m * 256 + ((c0 + np) >> 1), hp);
      // fp32 hidden_seq output (retires lazily)
      *(float2*)(out + ((size_t)(bm0 + m) * T_STEPS + t) * HS + c0 + np) = make_float2(h0, h1);
      if (t == T_STEPS - 1) {
        const size_t hs_total = (size_t)64 * T_STEPS * HS;
        *(float2*)(out + hs_total + (size_t)(bm0 + m) * HS + c0 + np) = make_float2(h0, h1);
        *(float2*)(out + hs_total + 64 * HS + (size_t)(bm0 + m) * HS + c0 + np) = make_float2(cA, cB);
      }
    }
#pragma unroll
    for (int gg = 0; gg < 4; ++gg) xwv[gg] = xwn[gg];
    // no end barrier: hl double-buffered; gl/cl rewrites fenced by sync A/B
  }
}

// ---------------------------------------------------------------------------
extern "C" void kernel_launch(void* const* d_in, const int* in_sizes, int n_in,
                              void* d_out, int out_size, void* d_ws, size_t ws_size,
                              hipStream_t stream) {
  const float* x = (const float*)d_in[0];
  const float* W = (const float*)d_in[1];
  const float* U = (const float*)d_in[2];
  const float* bias = (const float*)d_in[3];
  float* out = (float*)d_out;
  char* ws = (char*)d_ws;

  size_t off = 0;
  unsigned short* x_bf = (unsigned short*)(ws + off); off += (size_t)65536 * 512 * 2;       // 64MB
  unsigned short* Wt = (unsigned short*)(ws + off);   off += (size_t)2048 * 512 * 2;        // 2MB
  unsigned short* Ut = (unsigned short*)(ws + off);   off += (size_t)2048 * 512 * 2;        // 2MB
  unsigned* hist = (unsigned*)(ws + off);             off += (size_t)NGROUP * 1025 * 16384; // 67MB
  unsigned short* xWb = (unsigned short*)(ws + off);  off += (size_t)65536 * 2048 * 2;      // 256MB
  if (ws_size < off) return;  // workspace too small -> fail visibly

  conv_f32_to_bf16<<<4096, 256, 0, stream>>>(x, (uint4*)x_bf, 33554432 / 8);
  transpose_to_bf16<<<dim3(32, 8), 256, 0, stream>>>(W, Wt, 512, 2048);
  transpose_to_bf16<<<dim3(32, 8), 256, 0, stream>>>(U, Ut, 512, 2048);
  init_hist<<<2048, 256, 0, stream>>>((uint4*)hist);
  gemm_xw<<<dim3(16, 512), 256, 0, stream>>>(x_bf, Wt, xWb);
  lstm_seq<<<64, 256, 0, stream>>>((const unsigned*)xWb, Ut, bias, out, hist);
}